// Round 8
// baseline (309.412 us; speedup 1.0000x reference)
//
#include <hip/hip_runtime.h>
#include <hip/hip_bf16.h>

#define NROWS 8192
#define DDIM 64

typedef __attribute__((ext_vector_type(8))) short short8v;
typedef __attribute__((ext_vector_type(4))) float f32x4;

#define K2CONST 2.885390081777927f  /* log2(e)/TAU, TAU=0.5 */
#define EPSC 1e-8f

// ---------------- Kernel 1: row L2-normalize (bf16 P + scaled Pk) ----------
__global__ __launch_bounds__(256) void k_normalize(
    const float* __restrict__ z, const float* __restrict__ za,
    __hip_bfloat16* __restrict__ Pb, __hip_bfloat16* __restrict__ Pk,
    float* __restrict__ dI1, float* __restrict__ dI2, float* __restrict__ dX) {
  int wid = (blockIdx.x * blockDim.x + threadIdx.x) >> 6;
  int lane = threadIdx.x & 63;
  if (wid >= NROWS) return;
  float x = z[wid * DDIM + lane];
  float y = za[wid * DDIM + lane];
  float sx = x * x, sy = y * y, sxy = x * y;
  for (int m = 1; m < 64; m <<= 1) {
    sx  += __shfl_xor(sx, m);
    sy  += __shfl_xor(sy, m);
    sxy += __shfl_xor(sxy, m);
  }
  float inx = 1.0f / fmaxf(sqrtf(sx), 1e-12f);
  float iny = 1.0f / fmaxf(sqrtf(sy), 1e-12f);
  float xn = x * inx, yn = y * iny;
  Pb[wid * DDIM + lane] = __float2bfloat16(xn);
  Pb[(NROWS + wid) * DDIM + lane] = __float2bfloat16(yn);
  Pk[wid * DDIM + lane] = __float2bfloat16(xn * K2CONST);
  Pk[(NROWS + wid) * DDIM + lane] = __float2bfloat16(yn * K2CONST);
  if (lane == 0) {
    dI1[wid] = expf(sx * inx * inx * 2.0f);   // /TAU = *2
    dI2[wid] = expf(sy * iny * iny * 2.0f);
    dX[wid]  = expf(sxy * inx * iny * 2.0f);
  }
}

// ---------------- Kernel 2: fused gram row-sums + adj-masked sums ----------
// Transposed mfma: acc = mfma(colfrag, rowfrag_scaled). Lane (kq,r_in), reg c
// holds gram entry (i = tile_row + r_in, j = tile_col + kq*4 + c), already
// scaled by log2(e)/tau via Pk -> e = exp2(acc). adj mask: one float4/lane.
// 16 rows/wave, 512 cols/block (both quadrants) -> each adj byte read once.
// 4-deep adj prefetch ring + 2-deep P prefetch, fully unrolled (static idx).
__global__ __launch_bounds__(256) void k_fused(
    const __hip_bfloat16* __restrict__ Pb, const __hip_bfloat16* __restrict__ Pk,
    const float* __restrict__ adj, const float* __restrict__ adj_aug,
    float* __restrict__ sD, float* __restrict__ sM, float* __restrict__ cnt) {
  int wave = threadIdx.x >> 6, lane = threadIdx.x & 63;
  int r_in = lane & 15, kq = lane >> 4;
  int rb = blockIdx.x >> 4;                 // 256 row-blocks of 64 rows
  int cb = blockIdx.x & 15;                 // 16 col-blocks of 512 cols
  int rowbase = rb * 64 + wave * 16;        // this wave: 16 gram rows
  int cbase = cb * 512;
  const float* ADJ = (rowbase < NROWS) ? adj : adj_aug;
  int arow0 = rowbase & (NROWS - 1);
  const float* adjp = ADJ + (size_t)(arow0 + r_in) * NROWS + cbase + kq * 4;

  const short8v* P8 = reinterpret_cast<const short8v*>(Pb);
  const short8v* K8 = reinterpret_cast<const short8v*>(Pk);
  int arow = rowbase + r_in;
  short8v a0 = K8[arow * 8 + kq];           // scaled row fragment (B operand)
  short8v a1 = K8[arow * 8 + kq + 4];

  f32x4 accD = (f32x4){0.f,0.f,0.f,0.f};
  f32x4 accM = (f32x4){0.f,0.f,0.f,0.f};
  f32x4 accC = (f32x4){0.f,0.f,0.f,0.f};

  short8v pb0[2], pb1[2], pc0[2], pc1[2];   // P col fragments, slot = ct&1
  f32x4 av[4];                              // adj ring, slot = ct&3

#define IP(S, CT) { int colA_ = cbase + ((CT) & 31) * 16 + r_in; \
    pb0[S] = P8[colA_ * 8 + kq]; pb1[S] = P8[colA_ * 8 + kq + 4]; \
    pc0[S] = P8[(colA_ + NROWS) * 8 + kq]; pc1[S] = P8[(colA_ + NROWS) * 8 + kq + 4]; }
#define IA(S, CT) av[S] = *(const f32x4*)(adjp + ((CT) & 31) * 16);

  IP(0, 0); IP(1, 1);
  IA(0, 0); IA(1, 1); IA(2, 2); IA(3, 3);

#pragma unroll
  for (int ct = 0; ct < 32; ct++) {
    const int cs = ct & 1;
    const int as = ct & 3;
    f32x4 g0 = (f32x4){0.f,0.f,0.f,0.f};
    g0 = __builtin_amdgcn_mfma_f32_16x16x32_bf16(pb0[cs], a0, g0, 0, 0, 0);
    g0 = __builtin_amdgcn_mfma_f32_16x16x32_bf16(pb1[cs], a1, g0, 0, 0, 0);
    f32x4 g1 = (f32x4){0.f,0.f,0.f,0.f};
    g1 = __builtin_amdgcn_mfma_f32_16x16x32_bf16(pc0[cs], a0, g1, 0, 0, 0);
    g1 = __builtin_amdgcn_mfma_f32_16x16x32_bf16(pc1[cs], a1, g1, 0, 0, 0);
    f32x4 acur = av[as];                    // consume before ring refill
    IP(cs, ct + 2);                         // P 2 ahead (L2-resident)
    IA(as, ct + 4);                         // adj 4 ahead (HBM)
#pragma unroll
    for (int c = 0; c < 4; c++) {
      float e = __builtin_amdgcn_exp2f(g0[c]) + __builtin_amdgcn_exp2f(g1[c]);
      accD[c] += e;
      accM[c] += acur[c] * e;
      accC[c] += acur[c];
    }
  }
#undef IP
#undef IA

  // horizontal sum over the lane's 4 j's, then reduce over kq (lane bits 4,5)
  float rD = accD[0] + accD[1] + accD[2] + accD[3];
  float rM = accM[0] + accM[1] + accM[2] + accM[3];
  float rC = accC[0] + accC[1] + accC[2] + accC[3];
#pragma unroll
  for (int m = 16; m < 64; m <<= 1) {
    rD += __shfl_xor(rD, m);
    rM += __shfl_xor(rM, m);
    rC += __shfl_xor(rC, m);
  }
  if (kq == 0) {
    atomicAdd(&sD[arow], rD);
    atomicAdd(&sM[arow], rM);
    atomicAdd(&cnt[arow], rC);
  }
}

// ---------------- Final: per-row loss, partial sums ----------------
__global__ __launch_bounds__(256) void k_final_partial(
    const float* __restrict__ sD, const float* __restrict__ sM,
    const float* __restrict__ dI1, const float* __restrict__ dI2,
    const float* __restrict__ dX,
    const float* __restrict__ cnt, float* __restrict__ acc) {
  int i = blockIdx.x * blockDim.x + threadIdx.x;  // 32 blocks x 256 = 8192
  float pos1 = dX[i] + sM[i];
  float den1 = sD[i] - dI1[i];
  float l1 = logf(pos1 / (den1 + EPSC) + EPSC) / (2.0f * cnt[i] + 1.0f);
  float pos2 = dX[i] + sM[NROWS + i];
  float den2 = sD[NROWS + i] - dI2[i];
  float l2 = logf(pos2 / (den2 + EPSC) + EPSC) / (2.0f * cnt[NROWS + i] + 1.0f);
  float local = l1 + l2;
#pragma unroll
  for (int m = 1; m < 64; m <<= 1) local += __shfl_xor(local, m);
  if ((threadIdx.x & 63) == 0) atomicAdd(acc, local);
}

__global__ void k_finalize(const float* __restrict__ acc, float* __restrict__ out) {
  out[0] = -acc[0] * (0.5f / (float)NROWS);
}

extern "C" void kernel_launch(void* const* d_in, const int* in_sizes, int n_in,
                              void* d_out, int out_size, void* d_ws, size_t ws_size,
                              hipStream_t stream) {
  const float* z       = (const float*)d_in[0];
  const float* za      = (const float*)d_in[1];
  const float* adj     = (const float*)d_in[2];
  const float* adj_aug = (const float*)d_in[3];

  float* ws = (float*)d_ws;
  __hip_bfloat16* Pb = (__hip_bfloat16*)ws;              // 16384*64 bf16
  __hip_bfloat16* Pk = (__hip_bfloat16*)(ws + 524288);   // scaled copy
  float* Z0   = ws + 1048576;   // zeroed region: 3*16384 + 1 floats
  float* sD   = Z0;             // 16384
  float* sM   = Z0 + 16384;     // 16384
  float* cnt  = Z0 + 32768;     // 16384
  float* acc  = Z0 + 49152;     // 1
  float* dI1  = Z0 + 49153;     // 8192
  float* dI2  = dI1 + 8192;     // 8192
  float* dX   = dI2 + 8192;     // 8192

  hipMemsetAsync(Z0, 0, 49153 * sizeof(float), stream);

  k_normalize<<<2048, 256, 0, stream>>>(z, za, Pb, Pk, dI1, dI2, dX);
  k_fused<<<4096, 256, 0, stream>>>(Pb, Pk, adj, adj_aug, sD, sM, cnt);
  k_final_partial<<<32, 256, 0, stream>>>(sD, sM, dI1, dI2, dX, cnt, acc);
  k_finalize<<<1, 1, 0, stream>>>(acc, (float*)d_out);
}

// Round 9
// 153.437 us; speedup vs baseline: 2.0165x; 2.0165x over previous
//
#include <hip/hip_runtime.h>
#include <hip/hip_bf16.h>

#define NROWS 8192
#define DDIM 64
#define GROWS 16384
#define BROWS 256          /* gram rows per block */
#define BCOLS 256          /* adj cols per block  */
#define CH 16              /* chunk rows          */
#define NCH 16             /* chunks per block    */

typedef __attribute__((ext_vector_type(8))) short short8v;
typedef __attribute__((ext_vector_type(4))) float f32x4;

#define K2CONST 2.885390081777927f  /* log2(e)/TAU, TAU=0.5 */
#define EPSC 1e-8f

#define AS1 __attribute__((address_space(1)))
#define AS3 __attribute__((address_space(3)))

// ---------------- Kernel 1: row L2-normalize (bf16 P + scaled Pk) ----------
__global__ __launch_bounds__(256) void k_normalize(
    const float* __restrict__ z, const float* __restrict__ za,
    __hip_bfloat16* __restrict__ Pb, __hip_bfloat16* __restrict__ Pk,
    float* __restrict__ dI1, float* __restrict__ dI2, float* __restrict__ dX) {
  int wid = (blockIdx.x * blockDim.x + threadIdx.x) >> 6;
  int lane = threadIdx.x & 63;
  if (wid >= NROWS) return;
  float x = z[wid * DDIM + lane];
  float y = za[wid * DDIM + lane];
  float sx = x * x, sy = y * y, sxy = x * y;
  for (int m = 1; m < 64; m <<= 1) {
    sx  += __shfl_xor(sx, m);
    sy  += __shfl_xor(sy, m);
    sxy += __shfl_xor(sxy, m);
  }
  float inx = 1.0f / fmaxf(sqrtf(sx), 1e-12f);
  float iny = 1.0f / fmaxf(sqrtf(sy), 1e-12f);
  float xn = x * inx, yn = y * iny;
  Pb[wid * DDIM + lane] = __float2bfloat16(xn);
  Pb[(NROWS + wid) * DDIM + lane] = __float2bfloat16(yn);
  Pk[wid * DDIM + lane] = __float2bfloat16(xn * K2CONST);
  Pk[(NROWS + wid) * DDIM + lane] = __float2bfloat16(yn * K2CONST);
  if (lane == 0) {
    dI1[wid] = expf(sx * inx * inx * 2.0f);   // /TAU = *2
    dI2[wid] = expf(sy * iny * iny * 2.0f);
    dX[wid]  = expf(sxy * iny * inx * 2.0f);
  }
}

// ---------------- Kernel 2: fused gram row-sums + adj-masked sums ----------
// Block: 256 gram rows x 256 adj cols. Col P-fragments in registers (fixed).
// Rows iterate in 16-row chunks; adj(16KB)+Pk(2KB) per chunk staged to LDS
// via global_load_lds, 4-slot ring, counted vmcnt (T3/T4), raw barriers.
// Compute: transposed mfma(colfrag, rowfrag): lane(r_in,kq) reg c holds gram
// (row=r_in, col=kq*4+c) -> adj is one aligned float4 per lane from LDS.
__global__ __launch_bounds__(256) void k_fused(
    const __hip_bfloat16* __restrict__ Pb, const __hip_bfloat16* __restrict__ Pk,
    const float* __restrict__ adj, const float* __restrict__ adj_aug,
    float* __restrict__ sD, float* __restrict__ sM, float* __restrict__ cnt) {
  __shared__ __align__(16) float ladj[4][CH][BCOLS];            // 64 KB
  __shared__ __align__(16) __hip_bfloat16 lpk[4][CH][DDIM];     //  8 KB

  const int tid = threadIdx.x;
  const int w = tid >> 6, lane = tid & 63;
  const int r_in = lane & 15, kq = lane >> 4;
  const int rb = blockIdx.x >> 5;          // 0..63 row-groups (of 256 gram rows)
  const int cb = blockIdx.x & 31;          // 0..31 col-groups (of 256 cols)
  const int grow0 = rb * BROWS;            // gram row base (0..16128)
  const int c0 = cb * BCOLS;
  const float* ADJ = (rb < 32) ? adj : adj_aug;
  const int arow0 = (rb & 31) * BROWS;

  // ---- col fragments (A operand), fixed per block: wave w owns 64 cols ----
  const short8v* P8 = reinterpret_cast<const short8v*>(Pb);
  short8v bA0[4], bA1[4], bB0[4], bB1[4];
#pragma unroll
  for (int t = 0; t < 4; t++) {
    int col = c0 + w * 64 + t * 16 + r_in;
    bA0[t] = P8[col * 8 + kq];
    bA1[t] = P8[col * 8 + kq + 4];
    bB0[t] = P8[(col + NROWS) * 8 + kq];
    bB1[t] = P8[(col + NROWS) * 8 + kq + 4];
  }

  // ---- staging: wave stages adj rows w*4..w*4+3 (1KB each);
  //      waves 0,1 additionally stage the two 1KB halves of the Pk chunk ----
#define STAGE(CC, SS) {                                                        \
    _Pragma("unroll")                                                          \
    for (int q = 0; q < 4; q++) {                                              \
      int r_ = w * 4 + q;                                                      \
      const float* gsrc_ = ADJ + (size_t)(arow0 + (CC) * CH + r_) * NROWS      \
                           + c0 + lane * 4;                                    \
      __builtin_amdgcn_global_load_lds(                                        \
          (const AS1 unsigned int*)gsrc_,                                      \
          (AS3 unsigned int*)&ladj[SS][r_][0], 16, 0, 0);                      \
    }                                                                          \
    if (w < 2) {                                                               \
      const __hip_bfloat16* psrc_ = Pk                                         \
          + (size_t)(grow0 + (CC) * CH + w * 8) * DDIM + lane * 8;             \
      __builtin_amdgcn_global_load_lds(                                        \
          (const AS1 unsigned int*)psrc_,                                      \
          (AS3 unsigned int*)&lpk[SS][w * 8][0], 16, 0, 0);                    \
    }                                                                          \
  }

  STAGE(0, 0); STAGE(1, 1); STAGE(2, 2);

  for (int k = 0; k < NCH; k++) {
    STAGE((k + 3) & 15, (k + 3) & 3);      // &15 wrap: uniform count, in-bounds
    if (w < 2) asm volatile("s_waitcnt vmcnt(15)" ::: "memory");
    else       asm volatile("s_waitcnt vmcnt(12)" ::: "memory");
    __builtin_amdgcn_s_barrier();

    const int ss = k & 3;
    short8v a0 = *(const short8v*)&lpk[ss][r_in][kq * 8];       // rows, dims 0-31
    short8v a1 = *(const short8v*)&lpk[ss][r_in][kq * 8 + 32];  // rows, dims 32-63
    float dsum = 0.f, msum = 0.f, csum = 0.f;
#pragma unroll
    for (int t = 0; t < 4; t++) {
      f32x4 av = *(const f32x4*)&ladj[ss][r_in][w * 64 + t * 16 + kq * 4];
      f32x4 g0 = (f32x4){0.f, 0.f, 0.f, 0.f};
      g0 = __builtin_amdgcn_mfma_f32_16x16x32_bf16(bA0[t], a0, g0, 0, 0, 0);
      g0 = __builtin_amdgcn_mfma_f32_16x16x32_bf16(bA1[t], a1, g0, 0, 0, 0);
      f32x4 g1 = (f32x4){0.f, 0.f, 0.f, 0.f};
      g1 = __builtin_amdgcn_mfma_f32_16x16x32_bf16(bB0[t], a0, g1, 0, 0, 0);
      g1 = __builtin_amdgcn_mfma_f32_16x16x32_bf16(bB1[t], a1, g1, 0, 0, 0);
#pragma unroll
      for (int c = 0; c < 4; c++) {
        float e = __builtin_amdgcn_exp2f(g0[c]) + __builtin_amdgcn_exp2f(g1[c]);
        dsum += e;
        msum += av[c] * e;
        csum += av[c];
      }
    }
    // reduce over kq (lane bits 4,5): lanes 0-15 hold row totals for 64 cols
    dsum += __shfl_xor(dsum, 16); dsum += __shfl_xor(dsum, 32);
    msum += __shfl_xor(msum, 16); msum += __shfl_xor(msum, 32);
    csum += __shfl_xor(csum, 16); csum += __shfl_xor(csum, 32);
    if (lane < 16) {
      int row = grow0 + k * CH + r_in;
      atomicAdd(&sD[row], dsum);
      atomicAdd(&sM[row], msum);
      atomicAdd(&cnt[row], csum);
    }
    __builtin_amdgcn_s_barrier();          // protect ring slot before restage
  }
#undef STAGE
}

// ---------------- Final: per-row loss, partial sums ----------------
__global__ __launch_bounds__(256) void k_final_partial(
    const float* __restrict__ sD, const float* __restrict__ sM,
    const float* __restrict__ dI1, const float* __restrict__ dI2,
    const float* __restrict__ dX,
    const float* __restrict__ cnt, float* __restrict__ acc) {
  int i = blockIdx.x * blockDim.x + threadIdx.x;  // 32 blocks x 256 = 8192
  float pos1 = dX[i] + sM[i];
  float den1 = sD[i] - dI1[i];
  float l1 = logf(pos1 / (den1 + EPSC) + EPSC) / (2.0f * cnt[i] + 1.0f);
  float pos2 = dX[i] + sM[NROWS + i];
  float den2 = sD[NROWS + i] - dI2[i];
  float l2 = logf(pos2 / (den2 + EPSC) + EPSC) / (2.0f * cnt[NROWS + i] + 1.0f);
  float local = l1 + l2;
#pragma unroll
  for (int m = 1; m < 64; m <<= 1) local += __shfl_xor(local, m);
  if ((threadIdx.x & 63) == 0) atomicAdd(acc, local);
}

__global__ void k_finalize(const float* __restrict__ acc, float* __restrict__ out) {
  out[0] = -acc[0] * (0.5f / (float)NROWS);
}

extern "C" void kernel_launch(void* const* d_in, const int* in_sizes, int n_in,
                              void* d_out, int out_size, void* d_ws, size_t ws_size,
                              hipStream_t stream) {
  const float* z       = (const float*)d_in[0];
  const float* za      = (const float*)d_in[1];
  const float* adj     = (const float*)d_in[2];
  const float* adj_aug = (const float*)d_in[3];

  float* ws = (float*)d_ws;
  __hip_bfloat16* Pb = (__hip_bfloat16*)ws;              // 16384*64 bf16
  __hip_bfloat16* Pk = (__hip_bfloat16*)(ws + 524288);   // scaled copy
  float* Z0   = ws + 1048576;   // zeroed region: 3*16384 + 1 floats
  float* sD   = Z0;             // 16384
  float* sM   = Z0 + 16384;     // 16384
  float* cnt  = Z0 + 32768;     // 16384
  float* acc  = Z0 + 49152;     // 1
  float* dI1  = Z0 + 49153;     // 8192
  float* dI2  = dI1 + 8192;     // 8192
  float* dX   = dI2 + 8192;     // 8192

  hipMemsetAsync(Z0, 0, 49153 * sizeof(float), stream);

  k_normalize<<<2048, 256, 0, stream>>>(z, za, Pb, Pk, dI1, dI2, dX);
  k_fused<<<2048, 256, 0, stream>>>(Pb, Pk, adj, adj_aug, sD, sM, cnt);
  k_final_partial<<<32, 256, 0, stream>>>(sD, sM, dI1, dI2, dX, cnt, acc);
  k_finalize<<<1, 1, 0, stream>>>(acc, (float*)d_out);
}

// Round 10
// 148.412 us; speedup vs baseline: 2.0848x; 1.0339x over previous
//
#include <hip/hip_runtime.h>
#include <hip/hip_bf16.h>

#define NROWS 8192
#define DDIM 64
#define GROWS 16384
#define BROWS 256          /* gram rows per block */
#define BCOLS 256          /* adj cols per block  */
#define CH 16              /* chunk rows          */
#define NCH 16             /* chunks per block    */

typedef __attribute__((ext_vector_type(8))) short short8v;
typedef __attribute__((ext_vector_type(4))) float f32x4;

#define K2CONST 2.885390081777927f  /* log2(e)/TAU, TAU=0.5 */
#define EPSC 1e-8f

#define AS1 __attribute__((address_space(1)))
#define AS3 __attribute__((address_space(3)))

// ---------------- Kernel 1: row L2-normalize (bf16 P + scaled Pk) ----------
__global__ __launch_bounds__(256) void k_normalize(
    const float* __restrict__ z, const float* __restrict__ za,
    __hip_bfloat16* __restrict__ Pb, __hip_bfloat16* __restrict__ Pk,
    float* __restrict__ dI1, float* __restrict__ dI2, float* __restrict__ dX) {
  int wid = (blockIdx.x * blockDim.x + threadIdx.x) >> 6;
  int lane = threadIdx.x & 63;
  if (wid >= NROWS) return;
  float x = z[wid * DDIM + lane];
  float y = za[wid * DDIM + lane];
  float sx = x * x, sy = y * y, sxy = x * y;
  for (int m = 1; m < 64; m <<= 1) {
    sx  += __shfl_xor(sx, m);
    sy  += __shfl_xor(sy, m);
    sxy += __shfl_xor(sxy, m);
  }
  float inx = 1.0f / fmaxf(sqrtf(sx), 1e-12f);
  float iny = 1.0f / fmaxf(sqrtf(sy), 1e-12f);
  float xn = x * inx, yn = y * iny;
  Pb[wid * DDIM + lane] = __float2bfloat16(xn);
  Pb[(NROWS + wid) * DDIM + lane] = __float2bfloat16(yn);
  Pk[wid * DDIM + lane] = __float2bfloat16(xn * K2CONST);
  Pk[(NROWS + wid) * DDIM + lane] = __float2bfloat16(yn * K2CONST);
  if (lane == 0) {
    dI1[wid] = expf(sx * inx * inx * 2.0f);   // /TAU = *2
    dI2[wid] = expf(sy * iny * iny * 2.0f);
    dX[wid]  = expf(sxy * iny * inx * 2.0f);
  }
}

// ---------------- Kernel 2: fused gram row-sums + adj-masked sums ----------
// Block: 256 gram rows x 256 adj cols. Col P-fragments in registers (fixed).
// Rows iterate in 16-row chunks; adj(16KB)+Pk(2KB) per chunk staged to LDS
// via global_load_lds, 4-slot ring, counted vmcnt (T3/T4), raw barriers.
// LDS XOR-swizzle (byte ^= (row&7)<<4) on BOTH tiles, both sides (rule #21):
// linear gload_lds dest + inverse-swizzled global source + swizzled read.
// Compute: transposed mfma(colfrag, rowfrag): lane(r_in,kq) reg c holds gram
// (row=r_in, col=kq*4+c) -> adj is one aligned float4 per lane from LDS.
__global__ __launch_bounds__(256) void k_fused(
    const __hip_bfloat16* __restrict__ Pb, const __hip_bfloat16* __restrict__ Pk,
    const float* __restrict__ adj, const float* __restrict__ adj_aug,
    float* __restrict__ sD, float* __restrict__ sM, float* __restrict__ cnt) {
  __shared__ __align__(16) float ladj[4][CH][BCOLS];            // 64 KB
  __shared__ __align__(16) __hip_bfloat16 lpk[4][CH][DDIM];     //  8 KB

  const int tid = threadIdx.x;
  const int w = tid >> 6, lane = tid & 63;
  const int r_in = lane & 15, kq = lane >> 4;
  const int rb = blockIdx.x >> 5;          // 0..63 row-groups (of 256 gram rows)
  const int cb = blockIdx.x & 31;          // 0..31 col-groups (of 256 cols)
  const int grow0 = rb * BROWS;            // gram row base (0..16128)
  const int c0 = cb * BCOLS;
  const float* ADJ = (rb < 32) ? adj : adj_aug;
  const int arow0 = (rb & 31) * BROWS;

  // ---- col fragments (A operand), fixed per block: wave w owns 64 cols ----
  const short8v* P8 = reinterpret_cast<const short8v*>(Pb);
  short8v bA0[4], bA1[4], bB0[4], bB1[4];
#pragma unroll
  for (int t = 0; t < 4; t++) {
    int col = c0 + w * 64 + t * 16 + r_in;
    bA0[t] = P8[col * 8 + kq];
    bA1[t] = P8[col * 8 + kq + 4];
    bB0[t] = P8[(col + NROWS) * 8 + kq];
    bB1[t] = P8[(col + NROWS) * 8 + kq + 4];
  }

  // ---- staging: wave stages adj rows w*4..w*4+3 (1KB each, src XOR-swizzled);
  //      waves 0,1 additionally stage the two 1KB halves of the Pk chunk ----
#define STAGE(CC, SS) {                                                        \
    _Pragma("unroll")                                                          \
    for (int q = 0; q < 4; q++) {                                              \
      int r_ = w * 4 + q;                                                      \
      const char* growb_ = (const char*)(ADJ                                   \
          + (size_t)(arow0 + (CC) * CH + r_) * NROWS + c0);                    \
      __builtin_amdgcn_global_load_lds(                                        \
          (const AS1 unsigned int*)(growb_ + ((lane * 16) ^ ((r_ & 7) << 4))), \
          (AS3 unsigned int*)&ladj[SS][r_][0], 16, 0, 0);                      \
    }                                                                          \
    if (w < 2) {                                                               \
      int prow_ = w * 8 + (lane >> 3);                                         \
      const char* pbase_ = (const char*)(Pk                                    \
          + (size_t)(grow0 + (CC) * CH + prow_) * DDIM);                       \
      __builtin_amdgcn_global_load_lds(                                        \
          (const AS1 unsigned int*)(pbase_                                     \
              + (((lane & 7) * 16) ^ (((lane >> 3) & 7) << 4))),               \
          (AS3 unsigned int*)&lpk[SS][w * 8][0], 16, 0, 0);                    \
    }                                                                          \
  }

  STAGE(0, 0); STAGE(1, 1); STAGE(2, 2);

  for (int k = 0; k < NCH; k++) {
    STAGE((k + 3) & 15, (k + 3) & 3);      // &15 wrap: uniform count, in-bounds
    if (w < 2) asm volatile("s_waitcnt vmcnt(15)" ::: "memory");
    else       asm volatile("s_waitcnt vmcnt(12)" ::: "memory");
    __builtin_amdgcn_s_barrier();

    const int ss = k & 3;
    const int swz = (r_in & 7) << 4;       // byte-XOR for this lane's row
    short8v a0 = *(const short8v*)((const char*)&lpk[ss][r_in][0]
                                   + ((kq * 16) ^ swz));
    short8v a1 = *(const short8v*)((const char*)&lpk[ss][r_in][0]
                                   + ((64 + kq * 16) ^ swz));
    float dsum = 0.f, msum = 0.f, csum = 0.f;
#pragma unroll
    for (int t = 0; t < 4; t++) {
      f32x4 av = *(const f32x4*)((const char*)&ladj[ss][r_in][0]
                                 + ((w * 256 + t * 64 + kq * 16) ^ swz));
      f32x4 g0 = (f32x4){0.f, 0.f, 0.f, 0.f};
      g0 = __builtin_amdgcn_mfma_f32_16x16x32_bf16(bA0[t], a0, g0, 0, 0, 0);
      g0 = __builtin_amdgcn_mfma_f32_16x16x32_bf16(bA1[t], a1, g0, 0, 0, 0);
      f32x4 g1 = (f32x4){0.f, 0.f, 0.f, 0.f};
      g1 = __builtin_amdgcn_mfma_f32_16x16x32_bf16(bB0[t], a0, g1, 0, 0, 0);
      g1 = __builtin_amdgcn_mfma_f32_16x16x32_bf16(bB1[t], a1, g1, 0, 0, 0);
#pragma unroll
      for (int c = 0; c < 4; c++) {
        float e = __builtin_amdgcn_exp2f(g0[c]) + __builtin_amdgcn_exp2f(g1[c]);
        dsum += e;
        msum += av[c] * e;
        csum += av[c];
      }
    }
    // reduce over kq (lane bits 4,5): lanes 0-15 hold row totals for 64 cols
    dsum += __shfl_xor(dsum, 16); dsum += __shfl_xor(dsum, 32);
    msum += __shfl_xor(msum, 16); msum += __shfl_xor(msum, 32);
    csum += __shfl_xor(csum, 16); csum += __shfl_xor(csum, 32);
    if (lane < 16) {
      int row = grow0 + k * CH + r_in;
      atomicAdd(&sD[row], dsum);
      atomicAdd(&sM[row], msum);
      atomicAdd(&cnt[row], csum);
    }
    __builtin_amdgcn_s_barrier();          // protect ring slot before restage
  }
#undef STAGE
}

// ---------------- Final: per-row loss, partial sums ----------------
__global__ __launch_bounds__(256) void k_final_partial(
    const float* __restrict__ sD, const float* __restrict__ sM,
    const float* __restrict__ dI1, const float* __restrict__ dI2,
    const float* __restrict__ dX,
    const float* __restrict__ cnt, float* __restrict__ acc) {
  int i = blockIdx.x * blockDim.x + threadIdx.x;  // 32 blocks x 256 = 8192
  float pos1 = dX[i] + sM[i];
  float den1 = sD[i] - dI1[i];
  float l1 = logf(pos1 / (den1 + EPSC) + EPSC) / (2.0f * cnt[i] + 1.0f);
  float pos2 = dX[i] + sM[NROWS + i];
  float den2 = sD[NROWS + i] - dI2[i];
  float l2 = logf(pos2 / (den2 + EPSC) + EPSC) / (2.0f * cnt[NROWS + i] + 1.0f);
  float local = l1 + l2;
#pragma unroll
  for (int m = 1; m < 64; m <<= 1) local += __shfl_xor(local, m);
  if ((threadIdx.x & 63) == 0) atomicAdd(acc, local);
}

__global__ void k_finalize(const float* __restrict__ acc, float* __restrict__ out) {
  out[0] = -acc[0] * (0.5f / (float)NROWS);
}

extern "C" void kernel_launch(void* const* d_in, const int* in_sizes, int n_in,
                              void* d_out, int out_size, void* d_ws, size_t ws_size,
                              hipStream_t stream) {
  const float* z       = (const float*)d_in[0];
  const float* za      = (const float*)d_in[1];
  const float* adj     = (const float*)d_in[2];
  const float* adj_aug = (const float*)d_in[3];

  float* ws = (float*)d_ws;
  __hip_bfloat16* Pb = (__hip_bfloat16*)ws;              // 16384*64 bf16
  __hip_bfloat16* Pk = (__hip_bfloat16*)(ws + 524288);   // scaled copy
  float* Z0   = ws + 1048576;   // zeroed region: 3*16384 + 1 floats
  float* sD   = Z0;             // 16384
  float* sM   = Z0 + 16384;     // 16384
  float* cnt  = Z0 + 32768;     // 16384
  float* acc  = Z0 + 49152;     // 1
  float* dI1  = Z0 + 49153;     // 8192
  float* dI2  = dI1 + 8192;     // 8192
  float* dX   = dI2 + 8192;     // 8192

  hipMemsetAsync(Z0, 0, 49153 * sizeof(float), stream);

  k_normalize<<<2048, 256, 0, stream>>>(z, za, Pb, Pk, dI1, dI2, dX);
  k_fused<<<2048, 256, 0, stream>>>(Pb, Pk, adj, adj_aug, sD, sM, cnt);
  k_final_partial<<<32, 256, 0, stream>>>(sD, sM, dI1, dI2, dX, cnt, acc);
  k_finalize<<<1, 1, 0, stream>>>(acc, (float*)d_out);
}